// Round 2
// baseline (121.994 us; speedup 1.0000x reference)
//
#include <hip/hip_runtime.h>
#include <hip/hip_bf16.h>

#define DIM   1024
#define HEADS 16
#define B     2
#define N     2048

typedef float f32x4 __attribute__((ext_vector_type(4)));

// ---------------------------------------------------------------------------
// Kernel 1: logits[b,h,n] = dot(x[b,n,:], W[h,:]) + bias[h]
// One block per (b,n). 256 threads = 4 waves; each wave computes 4 heads.
// Each lane holds 16 consecutive floats of the x row in registers (4 float4).
// ---------------------------------------------------------------------------
__global__ __launch_bounds__(256) void logits_kernel(
    const float* __restrict__ x, const float* __restrict__ W,
    const float* __restrict__ bias, float* __restrict__ logits) {
  const int bn   = blockIdx.x;            // b*N + n
  const int tid  = threadIdx.x;
  const int wave = tid >> 6;
  const int lane = tid & 63;

  const f32x4* xrow = (const f32x4*)(x + (size_t)bn * DIM);
  f32x4 xv[4];
#pragma unroll
  for (int k = 0; k < 4; ++k) xv[k] = xrow[lane * 4 + k];

#pragma unroll
  for (int hh = 0; hh < 4; ++hh) {
    const int h = wave * 4 + hh;
    const f32x4* wrow = (const f32x4*)(W + (size_t)h * DIM);
    float s = 0.0f;
#pragma unroll
    for (int k = 0; k < 4; ++k) {
      f32x4 wv = wrow[lane * 4 + k];
      s += wv.x * xv[k].x + wv.y * xv[k].y + wv.z * xv[k].z + wv.w * xv[k].w;
    }
    // 64-lane reduction
#pragma unroll
    for (int off = 32; off > 0; off >>= 1) s += __shfl_down(s, off, 64);
    if (lane == 0) {
      const int b = bn >> 11;   // / N
      const int n = bn & (N - 1);
      logits[((size_t)(b * HEADS + h)) * N + n] = s + bias[h];
    }
  }
}

// ---------------------------------------------------------------------------
// Kernel 2: fg[bh, :] = cumsum(logsigmoid(logits[bh, :]))
// One block per (b,h) = 32 blocks. 256 threads, 8 elements each (contiguous).
// ---------------------------------------------------------------------------
__device__ __forceinline__ float logsig(float z) {
  // stable: min(z,0) - log1p(exp(-|z|))
  return fminf(z, 0.0f) - log1pf(__expf(-fabsf(z)));
}

__global__ __launch_bounds__(256) void cumsum_kernel(
    const float* __restrict__ logits, float* __restrict__ fg) {
  const int bh  = blockIdx.x;
  const int tid = threadIdx.x;
  const float* lp = logits + (size_t)bh * N;
  float*       fp = fg     + (size_t)bh * N;

  f32x4 a = ((const f32x4*)lp)[tid * 2];
  f32x4 c = ((const f32x4*)lp)[tid * 2 + 1];
  float v[8] = {a.x, a.y, a.z, a.w, c.x, c.y, c.z, c.w};

  float run = 0.0f;
#pragma unroll
  for (int i = 0; i < 8; ++i) { v[i] = logsig(v[i]); run += v[i]; v[i] = run; }
  const float total = run;

  // inclusive wave scan of per-thread totals
  const int lane = tid & 63, wv = tid >> 6;
  float sc = total;
#pragma unroll
  for (int off = 1; off < 64; off <<= 1) {
    float t = __shfl_up(sc, off, 64);
    if (lane >= off) sc += t;
  }

  __shared__ float wtot[4];
  if (lane == 63) wtot[wv] = sc;
  __syncthreads();
  float wofs = 0.0f;
  for (int w = 0; w < wv; ++w) wofs += wtot[w];

  const float base = wofs + sc - total;  // exclusive prefix for this thread
  f32x4 o0 = {base + v[0], base + v[1], base + v[2], base + v[3]};
  f32x4 o1 = {base + v[4], base + v[5], base + v[6], base + v[7]};
  ((f32x4*)fp)[tid * 2]     = o0;
  ((f32x4*)fp)[tid * 2 + 1] = o1;
}

// ---------------------------------------------------------------------------
// Kernel 3: out[bh, i, j] = fg[bh, i] - fg[bh, j]
// One block per (bh, i) row. 256 threads × 2 float4 = 2048 floats per row.
// Streaming (nontemporal) stores — output is 512 MiB, write-bound.
// ---------------------------------------------------------------------------
__global__ __launch_bounds__(256) void outer_kernel(
    const float* __restrict__ fg, float* __restrict__ out) {
  const int row = blockIdx.x;             // (bh * N + i)
  const int bh  = row >> 11;              // / N
  const int i   = row & (N - 1);
  const float fi = fg[(size_t)bh * N + i];
  const f32x4* fj = (const f32x4*)(fg + (size_t)bh * N);
  f32x4* o = (f32x4*)(out + (size_t)row * N);
  const int tid = threadIdx.x;
#pragma unroll
  for (int k = 0; k < 2; ++k) {
    const int idx = tid + k * 256;        // float4 index 0..511
    f32x4 v = fj[idx];
    f32x4 r = {fi - v.x, fi - v.y, fi - v.z, fi - v.w};
    __builtin_nontemporal_store(r, &o[idx]);
  }
}

extern "C" void kernel_launch(void* const* d_in, const int* in_sizes, int n_in,
                              void* d_out, int out_size, void* d_ws, size_t ws_size,
                              hipStream_t stream) {
  const float* x    = (const float*)d_in[0];   // [B, N, DIM]
  const float* W    = (const float*)d_in[1];   // [HEADS, DIM]
  const float* bias = (const float*)d_in[2];   // [HEADS]
  float* out = (float*)d_out;                  // [B, HEADS, N, N]

  float* logits = (float*)d_ws;                            // B*HEADS*N f32 = 256 KB
  float* fg     = logits + (size_t)B * HEADS * N;          // B*HEADS*N f32 = 256 KB

  logits_kernel<<<B * N, 256, 0, stream>>>(x, W, bias, logits);
  cumsum_kernel<<<B * HEADS, 256, 0, stream>>>(logits, fg);
  outer_kernel<<<B * HEADS * N, 256, 0, stream>>>(fg, out);
}